// Round 1
// baseline (754.616 us; speedup 1.0000x reference)
//
#include <hip/hip_runtime.h>
#include <stdint.h>

#define M_TOTAL 16384
#define DIMS    64
#define CDIM    64
#define HID     100
#define NB      32
#define ROWS    64
#define DGRP    2
#define LS_C    107
#define AT_STRIDE 6408   // 100*64 + 8 pad words: breaks 3-way bank aliasing between matrices

#define W2ALL_ELEMS (DIMS*HID*128)   // 819200 u16 (bf16)
#define B2ALL_ELEMS (DIMS*128)       // 8192 f32
#define W1T_ELEMS   (3*HID*CDIM)     // 19200 f32

// ws layout (bytes)
#define W2ALL_OFF 0
#define B2ALL_OFF (W2ALL_ELEMS*2)                  // 1638400
#define W1T_OFF   (B2ALL_OFF + B2ALL_ELEMS*4)      // 1671168

__device__ __forceinline__ uint16_t f2bf(float f) {
  uint32_t u = __float_as_uint(f);
  return (uint16_t)((u + 0x8000u) >> 16);
}

__global__ void repack_kernel(
    const float* __restrict__ wW2, const float* __restrict__ wb2,
    const float* __restrict__ hW2, const float* __restrict__ hb2,
    const float* __restrict__ sW2, const float* __restrict__ sb2,
    const float* __restrict__ wW1, const float* __restrict__ hW1,
    const float* __restrict__ sW1,
    uint16_t* __restrict__ W2all, float* __restrict__ b2all,
    float* __restrict__ W1t)
{
  int i = blockIdx.x * 256 + threadIdx.x;
  if (i < W2ALL_ELEMS) {
    int c = i & 127;
    int t = i >> 7;        // d*100 + k
    int k = t % HID;
    int d = t / HID;
    float v = 0.f;
    if (c < 32)      v = wW2[k*2048 + d*32 + c];
    else if (c < 64) v = hW2[k*2048 + d*32 + (c-32)];
    else if (c < 97) v = sW2[k*2112 + d*33 + (c-64)];
    W2all[i] = f2bf(v);
    return;
  }
  i -= W2ALL_ELEMS;
  if (i < B2ALL_ELEMS) {
    int c = i & 127;
    int d = i >> 7;
    float v = 0.f;
    if (c < 32)      v = wb2[d*32 + c];
    else if (c < 64) v = hb2[d*32 + (c-32)];
    else if (c < 97) v = sb2[d*33 + (c-64)];
    b2all[i] = v;
    return;
  }
  i -= B2ALL_ELEMS;
  if (i < W1T_ELEMS) {
    int mat = i / (HID*CDIM);
    int r   = i % (HID*CDIM);
    int j = r >> 6;
    int k = r & 63;
    const float* W1 = (mat == 0) ? wW1 : (mat == 1) ? hW1 : sW1;
    W1t[i] = W1[k*HID + j];   // transpose: W1t[mat][j][k]
  }
}

union alignas(16) SharedU {
  float cond_s[ROWS*68];               // 17408 B (phase 1 only)
  struct {
    uint32_t Bs[HID*64];               // 25600 B: bf16 pairs, [k][64 words]
    float Ls[DGRP][ROWS][LS_C];        // 54784 B: f32 logits, odd stride
  } g;
};

__global__ __launch_bounds__(256, 1)
void spline_main(
    const float* __restrict__ X, const float* __restrict__ C,
    const int* __restrict__ pmask,
    const float* __restrict__ wb1, const float* __restrict__ hb1,
    const float* __restrict__ sb1,
    const uint16_t* __restrict__ W2all, const float* __restrict__ b2all,
    const float* __restrict__ W1t,
    float* __restrict__ Y, float* __restrict__ LADJ)
{
  __shared__ float At[3*AT_STRIDE];    // hidden^T: [mat][k=0..99][row=0..63], 76896 B
  __shared__ float LjLds[DGRP][ROWS];  // 512 B
  __shared__ SharedU U;                // 80384 B   (total ~157.8 KB)

  const int tid = threadIdx.x;
  const int r0 = blockIdx.x * ROWS;

  // ---- phase 0: stage cond tile [64][64] (padded stride 68) ----
  for (int i = tid; i < ROWS*CDIM; i += 256) {
    int r = i >> 6, c = i & 63;
    U.cond_s[r*68 + c] = C[(size_t)(r0 + r)*CDIM + c];
  }
  __syncthreads();

  // ---- phase 1: hidden = silu(cond@W1 + b1) -> At (transposed) ----
  {
    const int r = tid & 63;
    const int jg = __builtin_amdgcn_readfirstlane(tid >> 6);  // wave-uniform
    float creg[CDIM];
#pragma unroll
    for (int k = 0; k < CDIM; ++k) creg[k] = U.cond_s[r*68 + k];

    for (int mat = 0; mat < 3; ++mat) {
      const float* b1p = (mat == 0) ? wb1 : (mat == 1) ? hb1 : sb1;
      for (int j = jg; j < HID; j += 4) {
        const float* wrow = W1t + mat*(HID*CDIM) + j*CDIM;
        float a0 = 0.f, a1 = 0.f, a2 = 0.f, a3 = 0.f;
#pragma unroll
        for (int k = 0; k < CDIM; k += 4) {
          a0 = fmaf(creg[k+0], wrow[k+0], a0);
          a1 = fmaf(creg[k+1], wrow[k+1], a1);
          a2 = fmaf(creg[k+2], wrow[k+2], a2);
          a3 = fmaf(creg[k+3], wrow[k+3], a3);
        }
        float acc = ((a0 + a1) + (a2 + a3)) + b1p[j];
        float hv = acc / (1.f + __expf(-acc));       // silu
        At[mat*AT_STRIDE + j*64 + r] = hv;
      }
    }
  }
  __syncthreads();

  // ---- main loop over dims ----
  float ladj = 0.f;
  const int cx = tid & 63;
  const int ry = tid >> 6;
  const int matg = (cx < 16) ? 0 : (cx < 32) ? 1 : 2;  // cols 2cx,2cx+1: <32 w, <64 h, else s
  const float* Ab = At + matg*AT_STRIDE + ry*16;
  const int s_row = tid & 63;
  const int s_ds  = (tid >> 6) & 1;

  for (int d0 = 0; d0 < DIMS; d0 += DGRP) {
#pragma unroll 1
    for (int ds = 0; ds < DGRP; ++ds) {
      const int d = d0 + ds;
      __syncthreads();
      // stage Bs: one dim's 100x128 bf16 slice (contiguous)
      {
        const uint4* src = (const uint4*)(W2all + (size_t)d*HID*128);
        uint4* dst = (uint4*)U.g.Bs;
        for (int i = tid; i < HID*128/8; i += 256) dst[i] = src[i];
      }
      __syncthreads();

      // GEMM: logits[row][col] = sum_k At[mat][k][row] * Bs[k][col]
      float acc0[16], acc1[16];
#pragma unroll
      for (int i = 0; i < 16; ++i) { acc0[i] = 0.f; acc1[i] = 0.f; }
#pragma unroll 2
      for (int k = 0; k < HID; ++k) {
        float a[16];
        *(float4*)&a[0]  = *(const float4*)(Ab + k*64 + 0);
        *(float4*)&a[4]  = *(const float4*)(Ab + k*64 + 4);
        *(float4*)&a[8]  = *(const float4*)(Ab + k*64 + 8);
        *(float4*)&a[12] = *(const float4*)(Ab + k*64 + 12);
        uint32_t bp = U.g.Bs[k*64 + cx];
        float b0 = __uint_as_float(bp << 16);
        float b1 = __uint_as_float(bp & 0xffff0000u);
#pragma unroll
        for (int i = 0; i < 16; ++i) {
          acc0[i] = fmaf(a[i], b0, acc0[i]);
          acc1[i] = fmaf(a[i], b1, acc1[i]);
        }
      }
      if (cx < 49) {   // cols 0..97 useful (97 is zero pad, never read)
        float bb0 = b2all[d*128 + 2*cx + 0];
        float bb1 = b2all[d*128 + 2*cx + 1];
#pragma unroll
        for (int i = 0; i < 16; ++i) {
          int r = ry*16 + i;
          U.g.Ls[ds][r][2*cx + 0] = acc0[i] + bb0;
          U.g.Ls[ds][r][2*cx + 1] = acc1[i] + bb1;
        }
      }
    }
    __syncthreads();

    // ---- spline: 128 tasks, 1 thread = 1 (row, dim) ----
    if (tid < 64*DGRP) {
      const int d = d0 + s_ds;
      const float xv = X[(size_t)(r0 + s_row)*DIMS + d];
      const float* Lrow = U.g.Ls[s_ds][s_row];

      float l[NB];
      // widths softmax + cumsum + bin search
#pragma unroll
      for (int c = 0; c < NB; ++c) l[c] = Lrow[c];
      float mx = l[0];
#pragma unroll
      for (int c = 1; c < NB; ++c) mx = fmaxf(mx, l[c]);
      float ssum = 0.f;
#pragma unroll
      for (int c = 0; c < NB; ++c) { l[c] = __expf(l[c] - mx); ssum += l[c]; }
      float inv = 0.68f / ssum;    // (1 - 32*0.01)/sum

      int idx = 0;
      float cwk = -1.f;
      float wsel = fmaf(inv, l[0], 0.01f);
      float pref = wsel;
#pragma unroll
      for (int c = 1; c < NB; ++c) {
        float wc = fmaf(inv, l[c], 0.01f);
        float knot = fmaf(2.f, pref, -1.f);    // cw_c (interior knot c = 1..31)
        if (xv >= knot) { idx = c; cwk = knot; wsel = wc; }
        pref += wc;
      }
      float wk = (idx < NB-1) ? (2.f * wsel) : (1.f - cwk);  // cw[32] forced to RIGHT

      // heights softmax + partial cumsum at idx
#pragma unroll
      for (int c = 0; c < NB; ++c) l[c] = Lrow[NB + c];
      mx = l[0];
#pragma unroll
      for (int c = 1; c < NB; ++c) mx = fmaxf(mx, l[c]);
      float hsum = 0.f;
#pragma unroll
      for (int c = 0; c < NB; ++c) { l[c] = __expf(l[c] - mx); hsum += l[c]; }
      float invh = 0.68f / hsum;
      float hpref = 0.f, hsel = 0.f;
#pragma unroll
      for (int c = 0; c < NB; ++c) {
        float hc = fmaf(invh, l[c], 0.01f);
        hpref += (c < idx) ? hc : 0.f;
        if (c == idx) hsel = hc;
      }
      float chk = fmaf(2.f, hpref, -1.f);
      float hk = (idx < NB-1) ? (2.f * hsel) : (1.f - chk);

      // derivs (softplus), only slots idx and idx+1 needed; periodic ties slot 32 -> slot 0
      float sl0 = Lrow[2*NB + idx];
      float sl1;
      if (idx == NB-1) sl1 = (pmask[d] != 0) ? Lrow[2*NB + 0] : Lrow[2*NB + NB];
      else             sl1 = Lrow[2*NB + idx + 1];
      float dk  = 0.01f + ((sl0 > 15.f) ? sl0 : log1pf(__expf(sl0)));
      float dk1 = 0.01f + ((sl1 > 15.f) ? sl1 : log1pf(__expf(sl1)));

      // RQ spline eval
      float delta = hk / wk;
      float th  = (xv - cwk) / wk;
      float omt = 1.f - th;
      float t1m = th * omt;
      float th2 = th * th;
      float denom = delta + (dk1 + dk - 2.f*delta) * t1m;
      float yv = chk + hk * (delta*th2 + dk*t1m) / denom;
      float dnum = (delta*delta) * (dk1*th2 + 2.f*delta*t1m + dk*omt*omt);
      float deriv = dnum / (denom * denom);
      ladj += __logf(deriv);
      Y[(size_t)(r0 + s_row)*DIMS + d] = yv;
    }
  }

  if (tid < 64*DGRP) LjLds[s_ds][s_row] = ladj;
  __syncthreads();
  if (tid < 64) LADJ[r0 + tid] = LjLds[0][tid] + LjLds[1][tid];
}

extern "C" void kernel_launch(void* const* d_in, const int* in_sizes, int n_in,
                              void* d_out, int out_size, void* d_ws, size_t ws_size,
                              hipStream_t stream) {
  const float* x     = (const float*)d_in[0];
  const float* cond  = (const float*)d_in[1];
  const int*   pmask = (const int*)d_in[2];
  const float* wW1 = (const float*)d_in[3];
  const float* wb1 = (const float*)d_in[4];
  const float* wW2 = (const float*)d_in[5];
  const float* wb2 = (const float*)d_in[6];
  const float* hW1 = (const float*)d_in[7];
  const float* hb1 = (const float*)d_in[8];
  const float* hW2 = (const float*)d_in[9];
  const float* hb2 = (const float*)d_in[10];
  const float* sW1 = (const float*)d_in[11];
  const float* sb1 = (const float*)d_in[12];
  const float* sW2 = (const float*)d_in[13];
  const float* sb2 = (const float*)d_in[14];

  uint16_t* W2all = (uint16_t*)((char*)d_ws + W2ALL_OFF);
  float*    b2all = (float*)((char*)d_ws + B2ALL_OFF);
  float*    W1t   = (float*)((char*)d_ws + W1T_OFF);

  const int total = W2ALL_ELEMS + B2ALL_ELEMS + W1T_ELEMS;
  repack_kernel<<<(total + 255)/256, 256, 0, stream>>>(
      wW2, wb2, hW2, hb2, sW2, sb2, wW1, hW1, sW1, W2all, b2all, W1t);

  float* Y = (float*)d_out;
  float* LADJ = Y + (size_t)M_TOTAL*DIMS;
  spline_main<<<M_TOTAL/ROWS, 256, 0, stream>>>(
      x, cond, pmask, wb1, hb1, sb1, W2all, b2all, W1t, Y, LADJ);
}

// Round 2
// 278.722 us; speedup vs baseline: 2.7074x; 2.7074x over previous
//
#include <hip/hip_runtime.h>
#include <stdint.h>

#define M_TOTAL 16384
#define DIMS    64
#define CDIM    64
#define HID     100
#define NB      32
#define ROWS    64
#define DGRP    2
#define LS_C    108

typedef __bf16 bf16x8 __attribute__((ext_vector_type(8)));
typedef float  f32x4  __attribute__((ext_vector_type(4)));

// B ws layout: [d][cn 0..6][kg 0..13][col16][8]  (u16/bf16)
#define BKG        14
#define CN_STRIDE  (BKG*16*8)        // 1792 elems
#define DIM_STRIDE (7*CN_STRIDE)     // 12544 elems
#define W2M_ELEMS  (DIMS*DIM_STRIDE) // 802816
#define B2ALL_ELEMS (DIMS*128)       // 8192 f32
#define W1T_ELEMS  (3*HID*CDIM)      // 19200 f32
#define W2M_OFF   0
#define B2ALL_OFF (W2M_ELEMS*2)                 // 1605632
#define W1T_OFF   (B2ALL_OFF + B2ALL_ELEMS*4)   // 1638400  (total ws use ~1.72 MB)

__device__ __forceinline__ uint16_t f2bf(float f) {
  uint32_t u = __float_as_uint(f);
  return (uint16_t)((u + 0x8000u) >> 16);
}

__global__ void repack_kernel(
    const float* __restrict__ wW2, const float* __restrict__ wb2,
    const float* __restrict__ hW2, const float* __restrict__ hb2,
    const float* __restrict__ sW2, const float* __restrict__ sb2,
    const float* __restrict__ wW1, const float* __restrict__ hW1,
    const float* __restrict__ sW1,
    uint16_t* __restrict__ W2m, float* __restrict__ b2all,
    float* __restrict__ W1t)
{
  int i = blockIdx.x * 256 + threadIdx.x;
  if (i < W2M_ELEMS) {
    int j  = i & 7;
    int c  = (i >> 3) & 15;
    int t  = i >> 7;          // (d*7+cn)*14 + kg
    int kg = t % BKG;
    int t2 = t / BKG;         // d*7 + cn
    int cn = t2 % 7;
    int d  = t2 / 7;
    int k   = kg*8 + j;
    int col = cn*16 + c;
    float v = 0.f;
    if (k < HID) {
      if (col < 32)      v = wW2[k*2048 + d*32 + col];
      else if (col < 64) v = hW2[k*2048 + d*32 + (col-32)];
      else if (col < 97) v = sW2[k*2112 + d*33 + (col-64)];
    }
    W2m[i] = f2bf(v);
    return;
  }
  i -= W2M_ELEMS;
  if (i < B2ALL_ELEMS) {
    int c = i & 127;
    int d = i >> 7;
    float v = 0.f;
    if (c < 32)      v = wb2[d*32 + c];
    else if (c < 64) v = hb2[d*32 + (c-32)];
    else if (c < 97) v = sb2[d*33 + (c-64)];
    b2all[i] = v;
    return;
  }
  i -= B2ALL_ELEMS;
  if (i < W1T_ELEMS) {
    int mat = i / (HID*CDIM);
    int r   = i % (HID*CDIM);
    int jj = r >> 6;
    int k  = r & 63;
    const float* W1 = (mat == 0) ? wW1 : (mat == 1) ? hW1 : sW1;
    W1t[i] = W1[k*HID + jj];   // W1t[mat][j][k]
  }
}

union alignas(16) SharedU {
  float cond_s[ROWS*68];                 // 17408 B (phase 0/1 only)
  struct {
    uint16_t Bs[DGRP*DIM_STRIDE];        // 50176 B: 2 dims of B fragments
    float Ls[DGRP][ROWS][LS_C];          // 55296 B: f32 logits
  } g;
};

__global__ __launch_bounds__(256, 1)
void spline_main(
    const float* __restrict__ X, const float* __restrict__ C,
    const int* __restrict__ pmask,
    const float* __restrict__ wb1, const float* __restrict__ hb1,
    const float* __restrict__ sb1,
    const uint16_t* __restrict__ W2m, const float* __restrict__ b2all,
    const float* __restrict__ W1t,
    float* __restrict__ Y, float* __restrict__ LADJ)
{
  __shared__ uint16_t At[3*16*64*8];     // 49152 B: A frags [mat][kg16][row64][8]
  __shared__ float LjLds[DGRP][ROWS];    // 512 B
  __shared__ SharedU U;                  // 105472 B  (total 155136 B)

  const int tid = threadIdx.x;
  const int r0 = blockIdx.x * ROWS;

  // ---- phase 0: stage cond tile ----
  for (int i = tid; i < ROWS*CDIM; i += 256) {
    int r = i >> 6, c = i & 63;
    U.cond_s[r*68 + c] = C[(size_t)(r0 + r)*CDIM + c];
  }
  __syncthreads();

  // ---- phase 1: hidden = silu(cond@W1+b1) -> At (bf16, MFMA A layout), zero-pad j>=100 ----
  {
    const int r  = tid & 63;
    const int jg = tid >> 6;
    float creg[CDIM];
#pragma unroll
    for (int k = 0; k < CDIM; ++k) creg[k] = U.cond_s[r*68 + k];

    for (int mat = 0; mat < 3; ++mat) {
      const float* b1p = (mat == 0) ? wb1 : (mat == 1) ? hb1 : sb1;
      for (int j = jg; j < 128; j += 4) {
        float hv = 0.f;
        if (j < HID) {
          const float* wrow = W1t + mat*(HID*CDIM) + j*CDIM;
          float a0 = 0.f, a1 = 0.f, a2 = 0.f, a3 = 0.f;
#pragma unroll
          for (int k = 0; k < CDIM; k += 4) {
            a0 = fmaf(creg[k+0], wrow[k+0], a0);
            a1 = fmaf(creg[k+1], wrow[k+1], a1);
            a2 = fmaf(creg[k+2], wrow[k+2], a2);
            a3 = fmaf(creg[k+3], wrow[k+3], a3);
          }
          float acc = ((a0 + a1) + (a2 + a3)) + b1p[j];
          hv = acc / (1.f + __expf(-acc));
        }
        At[mat*8192 + (j>>3)*512 + r*8 + (j&7)] = f2bf(hv);
      }
    }
  }

  const int lane = tid & 63;
  const int w    = tid >> 6;
  const int l15  = lane & 15;
  const int lkg  = lane >> 4;
  const int g_ds = w >> 1;           // which of the 2 dims this wave computes
  const bool evenw = (w & 1) == 0;   // even wave: w+h cols (mats 0,1); odd: s cols (mat 2)
  const int s_row = tid & 63;
  const int s_ds  = (tid >> 6) & 1;
  float ladj = 0.f;

  // ---- spline evaluator (reads Ls[s_ds][s_row]) ----
  auto do_spline = [&](int dbase) {
    if (tid < 64*DGRP) {
      const int d = dbase + s_ds;
      const float xv = X[(size_t)(r0 + s_row)*DIMS + d];
      const float* Lrow = &U.g.Ls[s_ds][s_row][0];

      float l[NB];
#pragma unroll
      for (int q = 0; q < 8; ++q) *(float4*)&l[4*q] = *(const float4*)(Lrow + 4*q);
      float mx = l[0];
#pragma unroll
      for (int c = 1; c < NB; ++c) mx = fmaxf(mx, l[c]);
      float ssum = 0.f;
#pragma unroll
      for (int c = 0; c < NB; ++c) { l[c] = __expf(l[c] - mx); ssum += l[c]; }
      float inv = 0.68f / ssum;

      int idx = 0;
      float cwk = -1.f;
      float wsel = fmaf(inv, l[0], 0.01f);
      float pref = wsel;
#pragma unroll
      for (int c = 1; c < NB; ++c) {
        float wc = fmaf(inv, l[c], 0.01f);
        float knot = fmaf(2.f, pref, -1.f);
        if (xv >= knot) { idx = c; cwk = knot; wsel = wc; }
        pref += wc;
      }
      float wk = (idx < NB-1) ? (2.f * wsel) : (1.f - cwk);

#pragma unroll
      for (int q = 0; q < 8; ++q) *(float4*)&l[4*q] = *(const float4*)(Lrow + NB + 4*q);
      mx = l[0];
#pragma unroll
      for (int c = 1; c < NB; ++c) mx = fmaxf(mx, l[c]);
      float hsum = 0.f;
#pragma unroll
      for (int c = 0; c < NB; ++c) { l[c] = __expf(l[c] - mx); hsum += l[c]; }
      float invh = 0.68f / hsum;
      float hpref = 0.f, hsel = 0.f;
#pragma unroll
      for (int c = 0; c < NB; ++c) {
        float hc = fmaf(invh, l[c], 0.01f);
        hpref += (c < idx) ? hc : 0.f;
        if (c == idx) hsel = hc;
      }
      float chk = fmaf(2.f, hpref, -1.f);
      float hk = (idx < NB-1) ? (2.f * hsel) : (1.f - chk);

      float sl0 = Lrow[2*NB + idx];
      float sl1;
      if (idx == NB-1) sl1 = (pmask[d] != 0) ? Lrow[2*NB + 0] : Lrow[2*NB + NB];
      else             sl1 = Lrow[2*NB + idx + 1];
      float dk  = 0.01f + ((sl0 > 15.f) ? sl0 : log1pf(__expf(sl0)));
      float dk1 = 0.01f + ((sl1 > 15.f) ? sl1 : log1pf(__expf(sl1)));

      float delta = hk / wk;
      float th  = (xv - cwk) / wk;
      float omt = 1.f - th;
      float t1m = th * omt;
      float th2 = th * th;
      float denom = delta + (dk1 + dk - 2.f*delta) * t1m;
      float yv = chk + hk * (delta*th2 + dk*t1m) / denom;
      float dnum = (delta*delta) * (dk1*th2 + 2.f*delta*t1m + dk*omt*omt);
      float deriv = dnum / (denom * denom);
      ladj += __logf(deriv);
      Y[(size_t)(r0 + s_row)*DIMS + d] = yv;
    }
  };

  // ---- MFMA tile worker: mats [cn_begin,cn_end) of dim d ----
  auto do_tiles = [&](int mat, int cn_begin, int cn_end, int d, const uint16_t* BsD) {
    bf16x8 af[4][4];
#pragma unroll
    for (int m = 0; m < 4; ++m)
#pragma unroll
      for (int ks = 0; ks < 4; ++ks)
        af[m][ks] = *(const bf16x8*)&At[mat*8192 + (ks*4 + lkg)*512 + (m*16 + l15)*8];
    for (int cn = cn_begin; cn < cn_end; ++cn) {
      bf16x8 bfr[4];
#pragma unroll
      for (int ks = 0; ks < 4; ++ks) {
        int kgb = ks*4 + lkg;
        if (kgb > BKG-1) kgb = BKG-1;        // A is zero there; read valid memory
        bfr[ks] = *(const bf16x8*)&BsD[cn*CN_STRIDE + kgb*128 + l15*8];
      }
      const int col = cn*16 + l15;
      const float bb = b2all[d*128 + col];
#pragma unroll
      for (int m = 0; m < 4; ++m) {
        f32x4 acc = {0.f, 0.f, 0.f, 0.f};
#pragma unroll
        for (int ks = 0; ks < 4; ++ks)
          acc = __builtin_amdgcn_mfma_f32_16x16x32_bf16(af[m][ks], bfr[ks], acc, 0, 0, 0);
        if (col < 97) {
#pragma unroll
          for (int r = 0; r < 4; ++r)
            U.g.Ls[g_ds][m*16 + lkg*4 + r][col] = acc[r] + bb;
        }
      }
    }
  };

  // ---- main loop over dim pairs ----
  for (int d0 = 0; d0 < DIMS; d0 += DGRP) {
    __syncthreads();   // GEMM(d0-2) done reading Bs / writing Ls; At ready (d0=0)
    // stage B fragments for dims d0, d0+1 (contiguous in ws)
    {
      const uint4* src = (const uint4*)(W2m + (size_t)d0 * DIM_STRIDE);
      uint4* dst = (uint4*)U.g.Bs;
      for (int i = tid; i < DGRP*DIM_STRIDE/8; i += 256) dst[i] = src[i];
    }
    if (d0 > 0) do_spline(d0 - DGRP);   // overlap spline(prev) with staging
    __syncthreads();
    // MFMA GEMM for this wave's dim
    const int d = d0 + g_ds;
    const uint16_t* BsD = U.g.Bs + g_ds*DIM_STRIDE;
    if (evenw) {
      do_tiles(0, 0, 2, d, BsD);   // w cols 0..31
      do_tiles(1, 2, 4, d, BsD);   // h cols 32..63
    } else {
      do_tiles(2, 4, 7, d, BsD);   // s cols 64..96 (+pad)
    }
  }
  __syncthreads();
  do_spline(DIMS - DGRP);

  if (tid < 64*DGRP) LjLds[s_ds][s_row] = ladj;
  __syncthreads();
  if (tid < 64) LADJ[r0 + tid] = LjLds[0][tid] + LjLds[1][tid];
}

extern "C" void kernel_launch(void* const* d_in, const int* in_sizes, int n_in,
                              void* d_out, int out_size, void* d_ws, size_t ws_size,
                              hipStream_t stream) {
  const float* x     = (const float*)d_in[0];
  const float* cond  = (const float*)d_in[1];
  const int*   pmask = (const int*)d_in[2];
  const float* wW1 = (const float*)d_in[3];
  const float* wb1 = (const float*)d_in[4];
  const float* wW2 = (const float*)d_in[5];
  const float* wb2 = (const float*)d_in[6];
  const float* hW1 = (const float*)d_in[7];
  const float* hb1 = (const float*)d_in[8];
  const float* hW2 = (const float*)d_in[9];
  const float* hb2 = (const float*)d_in[10];
  const float* sW1 = (const float*)d_in[11];
  const float* sb1 = (const float*)d_in[12];
  const float* sW2 = (const float*)d_in[13];
  const float* sb2 = (const float*)d_in[14];

  uint16_t* W2m   = (uint16_t*)((char*)d_ws + W2M_OFF);
  float*    b2all = (float*)((char*)d_ws + B2ALL_OFF);
  float*    W1t   = (float*)((char*)d_ws + W1T_OFF);

  const int total = W2M_ELEMS + B2ALL_ELEMS + W1T_ELEMS;
  repack_kernel<<<(total + 255)/256, 256, 0, stream>>>(
      wW2, wb2, hW2, hb2, sW2, sb2, wW1, hW1, sW1, W2m, b2all, W1t);

  float* Y = (float*)d_out;
  float* LADJ = Y + (size_t)M_TOTAL*DIMS;
  spline_main<<<M_TOTAL/ROWS, 256, 0, stream>>>(
      x, cond, pmask, wb1, hb1, sb1, W2m, b2all, W1t, Y, LADJ);
}

// Round 4
// 124.029 us; speedup vs baseline: 6.0842x; 2.2472x over previous
//
#include <hip/hip_runtime.h>
#include <stdint.h>

#define M_TOTAL 16384
#define DIMS    64
#define CDIM    64
#define HID     100
#define NB      32
#define ROWS    32
#define LS_C    108
#define LOG2E   1.4426950408889634f
#define LN2     0.6931471805599453f

typedef __bf16 bf16x8 __attribute__((ext_vector_type(8)));
typedef float  f32x4  __attribute__((ext_vector_type(4)));

// B ws layout: [d][cn 0..6][kg 0..13][col16][8] (bf16); w,h cols pre-scaled by log2(e)
#define BKG        14
#define CN_STRIDE  (BKG*16*8)        // 1792
#define DIM_STRIDE (7*CN_STRIDE)     // 12544
#define W2M_ELEMS  (DIMS*DIM_STRIDE) // 802816
#define B2ALL_ELEMS (DIMS*128)
#define W1T_ELEMS  (3*HID*CDIM)
#define W2M_OFF   0
#define B2ALL_OFF (W2M_ELEMS*2)
#define W1T_OFF   (B2ALL_OFF + B2ALL_ELEMS*4)

__device__ __forceinline__ uint16_t f2bf(float f) {
  uint32_t u = __float_as_uint(f);
  return (uint16_t)((u + 0x8000u) >> 16);
}

__global__ void repack_kernel(
    const float* __restrict__ wW2, const float* __restrict__ wb2,
    const float* __restrict__ hW2, const float* __restrict__ hb2,
    const float* __restrict__ sW2, const float* __restrict__ sb2,
    const float* __restrict__ wW1, const float* __restrict__ hW1,
    const float* __restrict__ sW1,
    uint16_t* __restrict__ W2m, float* __restrict__ b2all,
    float* __restrict__ W1t)
{
  int i = blockIdx.x * 256 + threadIdx.x;
  if (i < W2M_ELEMS) {
    int j  = i & 7;
    int c  = (i >> 3) & 15;
    int t  = i >> 7;
    int kg = t % BKG;
    int t2 = t / BKG;
    int cn = t2 % 7;
    int d  = t2 / 7;
    int k   = kg*8 + j;
    int col = cn*16 + c;
    float v = 0.f;
    if (k < HID) {
      if (col < 32)      v = wW2[k*2048 + d*32 + col] * LOG2E;
      else if (col < 64) v = hW2[k*2048 + d*32 + (col-32)] * LOG2E;
      else if (col < 97) v = sW2[k*2112 + d*33 + (col-64)];
    }
    W2m[i] = f2bf(v);
    return;
  }
  i -= W2M_ELEMS;
  if (i < B2ALL_ELEMS) {
    int c = i & 127;
    int d = i >> 7;
    float v = 0.f;
    if (c < 32)      v = wb2[d*32 + c] * LOG2E;
    else if (c < 64) v = hb2[d*32 + (c-32)] * LOG2E;
    else if (c < 97) v = sb2[d*33 + (c-64)];
    b2all[i] = v;
    return;
  }
  i -= B2ALL_ELEMS;
  if (i < W1T_ELEMS) {
    int mat = i / (HID*CDIM);
    int r   = i % (HID*CDIM);
    int jj = r >> 6;
    int k  = r & 63;
    const float* W1 = (mat == 0) ? wW1 : (mat == 1) ? hW1 : sW1;
    W1t[i] = W1[k*HID + jj];
  }
}

union SharedU {
  struct { float cond_s[ROWS*68]; uint16_t At[3*16*ROWS*8]; } p;  // 8704 + 24576 B
  float Ls[2][2][ROWS][LS_C];                                     // 55296 B
};

__device__ __forceinline__ void gemm_range(
    const bf16x8 (&af)[2][4], float* Lbase, int cn0, int cn1, int d,
    const uint16_t* __restrict__ W2m, const float* __restrict__ b2all,
    int l15, int lkg)
{
  const uint16_t* Bd = W2m + (size_t)d * DIM_STRIDE;
  for (int cn = cn0; cn < cn1; ++cn) {
    bf16x8 bfr[4];
#pragma unroll
    for (int ks = 0; ks < 4; ++ks) {
      int kgb = ks*4 + lkg; if (kgb > BKG-1) kgb = BKG-1;   // A is zero there
      bfr[ks] = *(const bf16x8*)&Bd[cn*CN_STRIDE + kgb*128 + l15*8];
    }
    const int col = cn*16 + l15;
    const float bb = b2all[d*128 + col];
    f32x4 acc0 = {bb,bb,bb,bb}, acc1 = {bb,bb,bb,bb};
#pragma unroll
    for (int ks = 0; ks < 4; ++ks)
      acc0 = __builtin_amdgcn_mfma_f32_16x16x32_bf16(af[0][ks], bfr[ks], acc0, 0, 0, 0);
#pragma unroll
    for (int ks = 0; ks < 4; ++ks)
      acc1 = __builtin_amdgcn_mfma_f32_16x16x32_bf16(af[1][ks], bfr[ks], acc1, 0, 0, 0);
    if (cn < 4) {   // w,h cols: store exp(logit) = exp2(scaled logit)
#pragma unroll
      for (int r = 0; r < 4; ++r) {
        acc0[r] = __builtin_amdgcn_exp2f(acc0[r]);
        acc1[r] = __builtin_amdgcn_exp2f(acc1[r]);
      }
    }
    if (col < 97) {
#pragma unroll
      for (int r = 0; r < 4; ++r) {
        Lbase[(lkg*4 + r)*LS_C + col]      = acc0[r];
        Lbase[(16 + lkg*4 + r)*LS_C + col] = acc1[r];
      }
    }
  }
}

__global__ __launch_bounds__(256, 2)
void spline_main(
    const float* __restrict__ X, const float* __restrict__ C,
    const int* __restrict__ pmask,
    const float* __restrict__ wb1, const float* __restrict__ hb1,
    const float* __restrict__ sb1,
    const uint16_t* __restrict__ W2m, const float* __restrict__ b2all,
    const float* __restrict__ W1t,
    float* __restrict__ Y, float* __restrict__ LADJ)
{
  __shared__ SharedU U;            // 55296 B
  __shared__ float Xs[ROWS][65];   // 8320 B
  __shared__ float Ys[ROWS][65];   // 8320 B
  __shared__ float LDSw[64*33];    // 8448 B  (per-lane prefix scratch)

  const int tid = threadIdx.x;
  const int r0 = blockIdx.x * ROWS;

  // ---- phase 0: stage cond + X tiles ----
  for (int i = tid; i < ROWS*CDIM; i += 256) {
    int r = i >> 6, c = i & 63;
    U.p.cond_s[r*68 + c] = C[(size_t)(r0 + r)*CDIM + c];
    Xs[r][c] = X[(size_t)(r0 + r)*DIMS + c];
  }
  __syncthreads();

  // ---- phase 1: hidden = silu(cond@W1+b1) -> At (bf16, MFMA A layout), zero j>=100 ----
  {
    const int r  = tid & 31;
    const int jg = tid >> 5;
    float creg[CDIM];
#pragma unroll
    for (int k = 0; k < CDIM; ++k) creg[k] = U.p.cond_s[r*68 + k];
    for (int mat = 0; mat < 3; ++mat) {
      const float* b1p = (mat == 0) ? wb1 : (mat == 1) ? hb1 : sb1;
      for (int j = jg; j < 128; j += 8) {
        float hv = 0.f;
        if (j < HID) {
          const float* wrow = W1t + mat*(HID*CDIM) + j*CDIM;
          float a0 = 0.f, a1 = 0.f, a2 = 0.f, a3 = 0.f;
#pragma unroll
          for (int k = 0; k < CDIM; k += 4) {
            a0 = fmaf(creg[k+0], wrow[k+0], a0);
            a1 = fmaf(creg[k+1], wrow[k+1], a1);
            a2 = fmaf(creg[k+2], wrow[k+2], a2);
            a3 = fmaf(creg[k+3], wrow[k+3], a3);
          }
          float acc = ((a0 + a1) + (a2 + a3)) + b1p[j];
          hv = acc / (1.f + __expf(-acc));
        }
        U.p.At[mat*4096 + (j>>3)*256 + r*8 + (j&7)] = f2bf(hv);
      }
    }
  }
  __syncthreads();

  const int lane = tid & 63, w = tid >> 6;
  const int l15 = lane & 15, lkg = lane >> 4;
  const int sw = ((blockIdx.x >> 3) & 1) ? 3 : 0;     // spread spline waves across SIMDs
  const bool isSpl = (w == sw);
  const int gr = w - (w > sw ? 1 : 0);                // 0..2 for GEMM waves

  // hoist A fragments to registers (per-wave: its two mats)
  bf16x8 afA[2][4], afB[2][4];
  if (!isSpl) {
    int mA = (gr == 0) ? 0 : (gr == 1) ? 2 : 1;
    int mB = (gr == 0) ? 1 : (gr == 1) ? 0 : 2;
#pragma unroll
    for (int m = 0; m < 2; ++m)
#pragma unroll
      for (int ks = 0; ks < 4; ++ks) {
        afA[m][ks] = *(const bf16x8*)&U.p.At[mA*4096 + (ks*4+lkg)*256 + (m*16+l15)*8];
        afB[m][ks] = *(const bf16x8*)&U.p.At[mB*4096 + (ks*4+lkg)*256 + (m*16+l15)*8];
      }
  }
  __syncthreads();   // At reads done; Ls may now be written

  float ladj2 = 0.f;
  const int srow = lane & 31, sds = lane >> 5;

  for (int i = 0; i < 32; ++i) {
    const int d0 = 2*i, p = i & 1;
    if (!isSpl) {
      float* L0 = &U.Ls[p][0][0][0];
      float* L1 = &U.Ls[p][1][0][0];
      if (gr == 0) {
        gemm_range(afA, L0, 0, 2, d0,   W2m, b2all, l15, lkg);
        gemm_range(afB, L0, 2, 4, d0,   W2m, b2all, l15, lkg);
      } else if (gr == 1) {
        gemm_range(afA, L0, 4, 7, d0,   W2m, b2all, l15, lkg);
        gemm_range(afB, L1, 0, 2, d0+1, W2m, b2all, l15, lkg);
      } else {
        gemm_range(afA, L1, 2, 4, d0+1, W2m, b2all, l15, lkg);
        gemm_range(afB, L1, 4, 7, d0+1, W2m, b2all, l15, lkg);
      }
    }
    __syncthreads();   // Ls[p] ready; also fences spline(i-1) vs GEMM(i+1) on Ls[1-p]
    if (isSpl) {
      const int d = d0 + sds;
      const float* Lrow = &U.Ls[p][sds][srow][0];
      const float xv = Xs[srow][d];
      float e[32];
      // ---- widths (already exp'd by GEMM epilogue) ----
#pragma unroll
      for (int q = 0; q < 8; ++q) *(float4*)&e[4*q] = *(const float4*)(Lrow + 4*q);
      float P = 0.f;
#pragma unroll
      for (int c = 0; c < 32; ++c) { LDSw[lane*33 + c] = P; P += e[c]; }
      float rs = __builtin_amdgcn_rcpf(P);
      float Aa = (xv + 1.f) * 0.7352941176470588f * P;   // (x+1)/(2*0.68) * S
      float Uq = 0.014705882352941176f * P;              // 0.01/0.68 * S
      float T = Aa, Pc = 0.f, fidx = 0.f;
#pragma unroll
      for (int c = 1; c <= 31; ++c) {                    // x>=cw_c  <=>  P_c <= T_c
        Pc += e[c-1]; T -= Uq;
        fidx = (Pc <= T) ? (float)c : fidx;
      }
      const int idx = (int)fidx;
      const int idx1 = (idx < 31) ? idx + 1 : 31;
      float Psel = LDSw[lane*33 + idx];
      float Pip1 = LDSw[lane*33 + idx1];
      float cwk = fmaf(0.02f, fidx, -1.f) + 1.36f*rs*Psel;
      float wk  = (idx == 31) ? (1.f - cwk) : fmaf(1.36f*rs, Pip1 - Psel, 0.02f);
      // ---- heights ----
#pragma unroll
      for (int q = 0; q < 8; ++q) *(float4*)&e[4*q] = *(const float4*)(Lrow + 32 + 4*q);
      float P2 = 0.f;
#pragma unroll
      for (int c = 0; c < 32; ++c) { LDSw[lane*33 + c] = P2; P2 += e[c]; }
      float rs2 = __builtin_amdgcn_rcpf(P2);
      float P2sel = LDSw[lane*33 + idx];
      float P2ip1 = LDSw[lane*33 + idx1];
      float chk = fmaf(0.02f, fidx, -1.f) + 1.36f*rs2*P2sel;
      float hk  = (idx == 31) ? (1.f - chk) : fmaf(1.36f*rs2, P2ip1 - P2sel, 0.02f);
      // ---- slopes (raw logits, cols 64..96) ----
      float sl0 = Lrow[64 + idx];
      float sl1 = (idx < 31) ? Lrow[65 + idx]
                             : ((pmask[d] != 0) ? Lrow[64] : Lrow[96]);
      float dk  = fmaf(LN2, __builtin_amdgcn_logf(1.f + __builtin_amdgcn_exp2f(LOG2E*sl0)), 0.01f);
      float dk1 = fmaf(LN2, __builtin_amdgcn_logf(1.f + __builtin_amdgcn_exp2f(LOG2E*sl1)), 0.01f);
      // ---- RQ eval ----
      float rw = __builtin_amdgcn_rcpf(wk);
      float th = (xv - cwk)*rw;
      float delta = hk*rw;
      float omt = 1.f - th, t1m = th*omt, th2 = th*th;
      float denom = fmaf(dk1 + dk - 2.f*delta, t1m, delta);
      float rden = __builtin_amdgcn_rcpf(denom);
      float yv = fmaf(hk*fmaf(delta, th2, dk*t1m), rden, chk);
      float dn2 = fmaf(dk1, th2, fmaf(2.f*delta, t1m, dk*omt*omt));
      ladj2 += 2.f*(__builtin_amdgcn_logf(delta) - __builtin_amdgcn_logf(denom))
             + __builtin_amdgcn_logf(dn2);
      Ys[srow][d] = yv;
    }
  }

  if (isSpl) {
    float pl = __shfl_down(ladj2, 32);
    if (lane < 32) LADJ[r0 + lane] = LN2 * (ladj2 + pl);
  }
  __syncthreads();
  for (int i = tid; i < ROWS*DIMS; i += 256)
    Y[(size_t)(r0 + (i >> 6))*DIMS + (i & 63)] = Ys[i >> 6][i & 63];
}

extern "C" void kernel_launch(void* const* d_in, const int* in_sizes, int n_in,
                              void* d_out, int out_size, void* d_ws, size_t ws_size,
                              hipStream_t stream) {
  const float* x     = (const float*)d_in[0];
  const float* cond  = (const float*)d_in[1];
  const int*   pmask = (const int*)d_in[2];
  const float* wW1 = (const float*)d_in[3];
  const float* wb1 = (const float*)d_in[4];
  const float* wW2 = (const float*)d_in[5];
  const float* wb2 = (const float*)d_in[6];
  const float* hW1 = (const float*)d_in[7];
  const float* hb1 = (const float*)d_in[8];
  const float* hW2 = (const float*)d_in[9];
  const float* hb2 = (const float*)d_in[10];
  const float* sW1 = (const float*)d_in[11];
  const float* sb1 = (const float*)d_in[12];
  const float* sW2 = (const float*)d_in[13];
  const float* sb2 = (const float*)d_in[14];

  uint16_t* W2m   = (uint16_t*)((char*)d_ws + W2M_OFF);
  float*    b2all = (float*)((char*)d_ws + B2ALL_OFF);
  float*    W1t   = (float*)((char*)d_ws + W1T_OFF);

  const int total = W2M_ELEMS + B2ALL_ELEMS + W1T_ELEMS;
  repack_kernel<<<(total + 255)/256, 256, 0, stream>>>(
      wW2, wb2, hW2, hb2, sW2, sb2, wW1, hW1, sW1, W2m, b2all, W1t);

  float* Y = (float*)d_out;
  float* LADJ = Y + (size_t)M_TOTAL*DIMS;
  spline_main<<<M_TOTAL/ROWS, 256, 0, stream>>>(
      x, cond, pmask, wb1, hb1, sb1, W2m, b2all, W1t, Y, LADJ);
}

// Round 5
// 108.809 us; speedup vs baseline: 6.9353x; 1.1399x over previous
//
#include <hip/hip_runtime.h>
#include <stdint.h>

#define M_TOTAL 16384
#define DIMS    64
#define CDIM    64
#define HID     100
#define ROWS    32
#define LOG2E   1.4426950408889634f
#define LN2     0.6931471805599453f

typedef __bf16 bf16x8 __attribute__((ext_vector_type(8)));
typedef float  f32x4  __attribute__((ext_vector_type(4)));

// W2 ws layout: [d][cn 0..6][kg 0..13][col16][8] (bf16); w,h cols pre-scaled by log2(e)
#define BKG        14
#define CN_STRIDE  (BKG*16*8)        // 1792
#define DIM_STRIDE (7*CN_STRIDE)     // 12544
#define W2M_ELEMS  (DIMS*DIM_STRIDE) // 802816
#define B2ALL_ELEMS (DIMS*128)       // 8192 f32
#define W1M_ELEMS  (3*7*8*16*8)      // 21504 bf16: [mat][cn][kg8][col16][8]
#define B1_ELEMS   (3*112)           // 336 f32
#define W2M_OFF   0
#define B2ALL_OFF (W2M_ELEMS*2)                  // 1605632
#define W1M_OFF   (B2ALL_OFF + B2ALL_ELEMS*4)    // 1638400
#define B1_OFF    (W1M_OFF + W1M_ELEMS*2)        // 1681408  (end ~1682752)

__device__ __forceinline__ uint16_t f2bf(float f) {
  uint32_t u = __float_as_uint(f);
  return (uint16_t)((u + 0x8000u) >> 16);
}

__global__ void repack_kernel(
    const float* __restrict__ wW2, const float* __restrict__ wb2,
    const float* __restrict__ hW2, const float* __restrict__ hb2,
    const float* __restrict__ sW2, const float* __restrict__ sb2,
    const float* __restrict__ wW1, const float* __restrict__ hW1,
    const float* __restrict__ sW1,
    const float* __restrict__ wb1, const float* __restrict__ hb1,
    const float* __restrict__ sb1,
    uint16_t* __restrict__ W2m, float* __restrict__ b2all,
    uint16_t* __restrict__ W1m, float* __restrict__ b1all)
{
  int i = blockIdx.x * 256 + threadIdx.x;
  if (i < W2M_ELEMS) {
    int j  = i & 7;
    int c  = (i >> 3) & 15;
    int t  = i >> 7;
    int kg = t % BKG;
    int t2 = t / BKG;
    int cn = t2 % 7;
    int d  = t2 / 7;
    int k   = kg*8 + j;
    int col = cn*16 + c;
    float v = 0.f;
    if (k < HID) {
      if (col < 32)      v = wW2[k*2048 + d*32 + col] * LOG2E;
      else if (col < 64) v = hW2[k*2048 + d*32 + (col-32)] * LOG2E;
      else if (col < 97) v = sW2[k*2112 + d*33 + (col-64)];
    }
    W2m[i] = f2bf(v);
    return;
  }
  i -= W2M_ELEMS;
  if (i < B2ALL_ELEMS) {
    int c = i & 127;
    int d = i >> 7;
    float v = 0.f;
    if (c < 32)      v = wb2[d*32 + c] * LOG2E;
    else if (c < 64) v = hb2[d*32 + (c-32)] * LOG2E;
    else if (c < 97) v = sb2[d*33 + (c-64)];
    b2all[i] = v;
    return;
  }
  i -= B2ALL_ELEMS;
  if (i < W1M_ELEMS) {
    int jj = i & 7;
    int c  = (i >> 3) & 15;
    int kg = (i >> 7) & 7;
    int t  = i >> 10;         // mat*7 + cn
    int cn = t % 7;
    int mat = t / 7;
    int j = cn*16 + c;        // hidden unit
    int k = kg*8 + jj;        // cond dim
    const float* W1 = (mat == 0) ? wW1 : (mat == 1) ? hW1 : sW1;
    W1m[i] = f2bf((j < HID) ? W1[k*HID + j] : 0.f);
    return;
  }
  i -= W1M_ELEMS;
  if (i < B1_ELEMS) {
    int mat = i / 112, col = i % 112;
    const float* b1 = (mat == 0) ? wb1 : (mat == 1) ? hb1 : sb1;
    b1all[i] = (col < HID) ? b1[col] : 0.f;
  }
}

__global__ __launch_bounds__(256, 2)
void spline_main(
    const float* __restrict__ X, const float* __restrict__ C,
    const int* __restrict__ pmask,
    const uint16_t* __restrict__ W2m, const float* __restrict__ b2all,
    const uint16_t* __restrict__ W1m, const float* __restrict__ b1all,
    float* __restrict__ Y, float* __restrict__ LADJ)
{
  __shared__ union {
    struct { float cond_s[ROWS*68]; uint16_t At[3*16*ROWS*8]; } p;  // 8704 + 24576
    float Ls[4][ROWS*100];                                          // 51200
  } U;
  __shared__ float LjLds[4][ROWS];   // 512    total ~51.7 KB

  const int tid = threadIdx.x;
  const int r0 = blockIdx.x * ROWS;
  const int lane = tid & 63, wv = tid >> 6;
  const int l15 = lane & 15, lkg = lane >> 4;
  const int hb = lane >> 5;          // 0: widths pipe, 1: heights pipe
  const int srow = lane & 31;

  // ---- phase 0: stage cond tile ----
  for (int i = tid; i < ROWS*CDIM; i += 256) {
    int r = i >> 6, c = i & 63;
    U.p.cond_s[r*68 + c] = C[(size_t)(r0 + r)*CDIM + c];
  }
  __syncthreads();

  // ---- phase 1: hidden = silu(cond@W1+b1) via MFMA -> At (bf16 A-frag layout) ----
  {
    bf16x8 cf[2][2];
#pragma unroll
    for (int m = 0; m < 2; ++m)
#pragma unroll
      for (int ks = 0; ks < 2; ++ks) {
        const float* cp = &U.p.cond_s[(m*16 + l15)*68 + ks*32 + lkg*8];
        float4 c0 = *(const float4*)cp;
        float4 c1 = *(const float4*)(cp + 4);
        union { uint16_t u[8]; bf16x8 v; } tmp;
        tmp.u[0]=f2bf(c0.x); tmp.u[1]=f2bf(c0.y); tmp.u[2]=f2bf(c0.z); tmp.u[3]=f2bf(c0.w);
        tmp.u[4]=f2bf(c1.x); tmp.u[5]=f2bf(c1.y); tmp.u[6]=f2bf(c1.z); tmp.u[7]=f2bf(c1.w);
        cf[m][ks] = tmp.v;
      }
    for (int t = wv; t < 21; t += 4) {
      int mat = t / 7, cn = t % 7;
      const uint16_t* Wb = W1m + (size_t)(mat*7 + cn)*1024;
      bf16x8 wf[2];
#pragma unroll
      for (int ks = 0; ks < 2; ++ks)
        wf[ks] = *(const bf16x8*)&Wb[(ks*4 + lkg)*128 + l15*8];
      f32x4 h0 = {0.f,0.f,0.f,0.f}, h1 = {0.f,0.f,0.f,0.f};
#pragma unroll
      for (int ks = 0; ks < 2; ++ks) {
        h0 = __builtin_amdgcn_mfma_f32_16x16x32_bf16(cf[0][ks], wf[ks], h0, 0, 0, 0);
        h1 = __builtin_amdgcn_mfma_f32_16x16x32_bf16(cf[1][ks], wf[ks], h1, 0, 0, 0);
      }
      float bb = b1all[mat*112 + cn*16 + l15];
      int j = cn*16 + l15;
      int base = mat*4096 + (j >> 3)*256 + (j & 7);
#pragma unroll
      for (int r = 0; r < 4; ++r) {
        float a0 = h0[r] + bb;
        float v0 = a0 * __builtin_amdgcn_rcpf(1.f + __builtin_amdgcn_exp2f(-LOG2E*a0));
        U.p.At[base + (lkg*4 + r)*8] = f2bf(v0);
        float a1 = h1[r] + bb;
        float v1 = a1 * __builtin_amdgcn_rcpf(1.f + __builtin_amdgcn_exp2f(-LOG2E*a1));
        U.p.At[base + (16 + lkg*4 + r)*8] = f2bf(v1);
      }
    }
    // zero-fill At kg 14,15 (K-padding: A must be 0 there)
    for (int i2 = tid; i2 < 768; i2 += 256) {
      int mat = i2 >> 8, q = i2 & 255;
      *(uint32_t*)&U.p.At[mat*4096 + 14*256 + q*2] = 0u;
    }
  }
  __syncthreads();

  // ---- hoist A fragments (all 3 mats) ----
  bf16x8 af[3][2][4];
#pragma unroll
  for (int mat = 0; mat < 3; ++mat)
#pragma unroll
    for (int m = 0; m < 2; ++m)
#pragma unroll
      for (int ks = 0; ks < 4; ++ks)
        af[mat][m][ks] = *(const bf16x8*)&U.p.At[mat*4096 + (ks*4 + lkg)*256 + (m*16 + l15)*8];
  __syncthreads();   // At reads done -> Ls region writable

  float* LsW = &U.Ls[wv][0];
  const int dbase = wv*16;
  float ladj2 = 0.f;
  float xq = 0.f; int pq = 0;

  // ---- spline for one dim, symmetric lanes (lo: widths+eval, hi: heights+slope2) ----
  auto SPLINE = [&](int d, float xv, int pm) {
    const float* Lr = LsW + srow*100 + hb*32;
    float e[32];
#pragma unroll
    for (int q = 0; q < 8; ++q) *(float4*)&e[4*q] = *(const float4*)(Lr + 4*q);
    // tree sum
    float s16[16];
#pragma unroll
    for (int k = 0; k < 16; ++k) s16[k] = e[2*k] + e[2*k+1];
#pragma unroll
    for (int k = 0; k < 8; ++k) s16[k] = s16[2*k] + s16[2*k+1];
#pragma unroll
    for (int k = 0; k < 4; ++k) s16[k] = s16[2*k] + s16[2*k+1];
    float S = (s16[0] + s16[1]) + (s16[2] + s16[3]);
    float rs = __builtin_amdgcn_rcpf(S);
    // binsearch (lo lanes meaningful; hi lanes harmless garbage)
    float Aa = (xv + 1.f) * 0.7352941176470588f * S;   // (x+1)/(2*0.68) * S
    float Uq = 0.014705882352941176f * S;              // 0.01/0.68 * S
    float T = Aa, Pc = 0.f, fidx = 0.f;
#pragma unroll
    for (int c = 1; c <= 31; ++c) {
      Pc += e[c-1]; T -= Uq;
      fidx = (Pc <= T) ? (float)c : fidx;
    }
    float foth = __shfl_xor(fidx, 32);
    float idxu = hb ? foth : fidx;       // broadcast lo's idx to hi
    // masked prefix (exact same fp-add order as cumsum) + e[idx] select
    float Psel = 0.f, esel = e[0];
#pragma unroll
    for (int c = 0; c < 32; ++c) {
      float cfv = (float)c;
      Psel += (cfv < idxu) ? e[c] : 0.f;
      esel  = (cfv == idxu) ? e[c] : esel;
    }
    float cK = fmaf(0.02f, idxu, -1.f) + 1.36f*rs*Psel;          // cwk / chk
    float wK = (idxu > 30.5f) ? (1.f - cK) : fmaf(1.36f*rs, esel, 0.02f);  // wk / hk
    // slope: lo takes d[idx], hi takes d[idx+1] (periodic tie at idx==31)
    int idxi = (int)idxu;
    int off = 64 + idxi + hb;
    if (hb && idxi == 31) off = pm ? 64 : 96;
    float sl = LsW[srow*100 + off];
    float dkv = fmaf(LN2, __builtin_amdgcn_logf(1.f + __builtin_amdgcn_exp2f(LOG2E*sl)), 0.01f);
    // exchange: lo receives hi's (chk, hk, dk1)
    float cO = __shfl_xor(cK, 32);
    float wO = __shfl_xor(wK, 32);
    float dO = __shfl_xor(dkv, 32);
    float cwk = cK, wk = wK, dk = dkv, chk = cO, hk = wO, dk1 = dO;
    float rw = __builtin_amdgcn_rcpf(wk);
    float th = (xv - cwk)*rw;
    float delta = hk*rw;
    float omt = 1.f - th, t1m = th*omt, th2 = th*th;
    float denom = fmaf(dk1 + dk - 2.f*delta, t1m, delta);
    float rden = __builtin_amdgcn_rcpf(denom);
    float yv = fmaf(hk*fmaf(delta, th2, dk*t1m), rden, chk);
    float dn2 = fmaf(dk1, th2, fmaf(2.f*delta, t1m, dk*omt*omt));
    ladj2 += 2.f*(__builtin_amdgcn_logf(delta) - __builtin_amdgcn_logf(denom))
           + __builtin_amdgcn_logf(dn2);
    if (!hb) Y[(size_t)(r0 + srow)*DIMS + d] = yv;
  };

  // ---- per-cn GEMM tile: 8 MFMA + epilogue ----
  auto do_cn = [&](const bf16x8 (&afm)[2][4], const bf16x8 (&B)[4],
                   float bb, int col, bool doexp) {
    f32x4 a0 = {bb,bb,bb,bb}, a1 = {bb,bb,bb,bb};
#pragma unroll
    for (int ks = 0; ks < 4; ++ks)
      a0 = __builtin_amdgcn_mfma_f32_16x16x32_bf16(afm[0][ks], B[ks], a0, 0, 0, 0);
#pragma unroll
    for (int ks = 0; ks < 4; ++ks)
      a1 = __builtin_amdgcn_mfma_f32_16x16x32_bf16(afm[1][ks], B[ks], a1, 0, 0, 0);
    if (doexp) {
#pragma unroll
      for (int r = 0; r < 4; ++r) {
        a0[r] = __builtin_amdgcn_exp2f(a0[r]);
        a1[r] = __builtin_amdgcn_exp2f(a1[r]);
      }
    }
    if (col < 97) {
#pragma unroll
      for (int r = 0; r < 4; ++r) {
        LsW[(lkg*4 + r)*100 + col]      = a0[r];
        LsW[(16 + lkg*4 + r)*100 + col] = a1[r];
      }
    }
  };

  // ---- main loop: 16 dims per wave, no barriers ----
#pragma unroll 1
  for (int dd = 0; dd < 16; ++dd) {
    const int d = dbase + dd;
    const uint16_t* Bd = W2m + (size_t)d*DIM_STRIDE;
    bf16x8 bf0[4][4];
#pragma unroll
    for (int cn = 0; cn < 4; ++cn)
#pragma unroll
      for (int ks = 0; ks < 4; ++ks) {
        int kgb = ks*4 + lkg; kgb = (kgb > 13) ? 13 : kgb;
        bf0[cn][ks] = *(const bf16x8*)&Bd[cn*CN_STRIDE + kgb*128 + l15*8];
      }
    float bbv[7];
#pragma unroll
    for (int cn = 0; cn < 7; ++cn) bbv[cn] = b2all[d*128 + cn*16 + l15];
    float xn = X[(size_t)(r0 + srow)*DIMS + d];
    int pn = pmask[d];

    if (dd > 0) SPLINE(d - 1, xq, pq);   // overlaps B-load latency
    xq = xn; pq = pn;

    bf16x8 bf1[3][4];
#pragma unroll
    for (int cn = 4; cn < 7; ++cn)
#pragma unroll
      for (int ks = 0; ks < 4; ++ks) {
        int kgb = ks*4 + lkg; kgb = (kgb > 13) ? 13 : kgb;
        bf1[cn-4][ks] = *(const bf16x8*)&Bd[cn*CN_STRIDE + kgb*128 + l15*8];
      }

    do_cn(af[0], bf0[0], bbv[0], 0*16 + l15, true);
    do_cn(af[0], bf0[1], bbv[1], 1*16 + l15, true);
    do_cn(af[1], bf0[2], bbv[2], 2*16 + l15, true);
    do_cn(af[1], bf0[3], bbv[3], 3*16 + l15, true);
    do_cn(af[2], bf1[0], bbv[4], 4*16 + l15, false);
    do_cn(af[2], bf1[1], bbv[5], 5*16 + l15, false);
    do_cn(af[2], bf1[2], bbv[6], 6*16 + l15, false);
  }
  SPLINE(dbase + 15, xq, pq);

  if (!hb) LjLds[wv][srow] = ladj2;
  __syncthreads();
  if (tid < ROWS)
    LADJ[r0 + tid] = LN2 * ((LjLds[0][tid] + LjLds[1][tid]) + (LjLds[2][tid] + LjLds[3][tid]));
}

extern "C" void kernel_launch(void* const* d_in, const int* in_sizes, int n_in,
                              void* d_out, int out_size, void* d_ws, size_t ws_size,
                              hipStream_t stream) {
  const float* x     = (const float*)d_in[0];
  const float* cond  = (const float*)d_in[1];
  const int*   pmask = (const int*)d_in[2];
  const float* wW1 = (const float*)d_in[3];
  const float* wb1 = (const float*)d_in[4];
  const float* wW2 = (const float*)d_in[5];
  const float* wb2 = (const float*)d_in[6];
  const float* hW1 = (const float*)d_in[7];
  const float* hb1 = (const float*)d_in[8];
  const float* hW2 = (const float*)d_in[9];
  const float* hb2 = (const float*)d_in[10];
  const float* sW1 = (const float*)d_in[11];
  const float* sb1 = (const float*)d_in[12];
  const float* sW2 = (const float*)d_in[13];
  const float* sb2 = (const float*)d_in[14];

  uint16_t* W2m   = (uint16_t*)((char*)d_ws + W2M_OFF);
  float*    b2all = (float*)((char*)d_ws + B2ALL_OFF);
  uint16_t* W1m   = (uint16_t*)((char*)d_ws + W1M_OFF);
  float*    b1all = (float*)((char*)d_ws + B1_OFF);

  const int total = W2M_ELEMS + B2ALL_ELEMS + W1M_ELEMS + B1_ELEMS;
  repack_kernel<<<(total + 255)/256, 256, 0, stream>>>(
      wW2, wb2, hW2, hb2, sW2, sb2, wW1, hW1, sW1, wb1, hb1, sb1,
      W2m, b2all, W1m, b1all);

  float* Y = (float*)d_out;
  float* LADJ = Y + (size_t)M_TOTAL*DIMS;
  spline_main<<<M_TOTAL/ROWS, 256, 0, stream>>>(
      x, cond, pmask, W2m, b2all, W1m, b1all, Y, LADJ);
}

// Round 6
// 64.723 us; speedup vs baseline: 11.6591x; 1.6811x over previous
//
#include <hip/hip_runtime.h>
#include <stdint.h>

#define M_TOTAL 16384
#define DIMS    64
#define CDIM    64
#define HID     100
#define ROWS    32
#define LOG2E   1.4426950408889634f
#define LN2     0.6931471805599453f

typedef __bf16 bf16x8 __attribute__((ext_vector_type(8)));
typedef float  f32x4  __attribute__((ext_vector_type(4)));

// W2 ws layout: [d][cn 0..6][kg 0..13][col16][8] (bf16); w,h cols pre-scaled by log2(e)
#define BKG        14
#define CN_STRIDE  (BKG*16*8)        // 1792
#define DIM_STRIDE (7*CN_STRIDE)     // 12544
#define W2M_ELEMS  (DIMS*DIM_STRIDE) // 802816
#define B2ALL_ELEMS (DIMS*128)       // 8192 f32
#define W1M_ELEMS  (3*7*8*16*8)      // 21504 bf16: [mat][cn][kg8][col16][8]
#define B1_ELEMS   (3*112)           // 336 f32
#define W2M_OFF   0
#define B2ALL_OFF (W2M_ELEMS*2)                  // 1605632
#define W1M_OFF   (B2ALL_OFF + B2ALL_ELEMS*4)    // 1638400
#define B1_OFF    (W1M_OFF + W1M_ELEMS*2)        // 1681408

__device__ __forceinline__ uint16_t f2bf(float f) {
  uint32_t u = __float_as_uint(f);
  return (uint16_t)((u + 0x8000u) >> 16);
}

__global__ void repack_kernel(
    const float* __restrict__ wW2, const float* __restrict__ wb2,
    const float* __restrict__ hW2, const float* __restrict__ hb2,
    const float* __restrict__ sW2, const float* __restrict__ sb2,
    const float* __restrict__ wW1, const float* __restrict__ hW1,
    const float* __restrict__ sW1,
    const float* __restrict__ wb1, const float* __restrict__ hb1,
    const float* __restrict__ sb1,
    uint16_t* __restrict__ W2m, float* __restrict__ b2all,
    uint16_t* __restrict__ W1m, float* __restrict__ b1all)
{
  int i = blockIdx.x * 256 + threadIdx.x;
  if (i < W2M_ELEMS) {
    int j  = i & 7;
    int c  = (i >> 3) & 15;
    int t  = i >> 7;
    int kg = t % BKG;
    int t2 = t / BKG;
    int cn = t2 % 7;
    int d  = t2 / 7;
    int k   = kg*8 + j;
    int col = cn*16 + c;
    float v = 0.f;
    if (k < HID) {
      if (col < 32)      v = wW2[k*2048 + d*32 + col] * LOG2E;
      else if (col < 64) v = hW2[k*2048 + d*32 + (col-32)] * LOG2E;
      else if (col < 97) v = sW2[k*2112 + d*33 + (col-64)];
    }
    W2m[i] = f2bf(v);
    return;
  }
  i -= W2M_ELEMS;
  if (i < B2ALL_ELEMS) {
    int c = i & 127;
    int d = i >> 7;
    float v = 0.f;
    if (c < 32)      v = wb2[d*32 + c] * LOG2E;
    else if (c < 64) v = hb2[d*32 + (c-32)] * LOG2E;
    else if (c < 97) v = sb2[d*33 + (c-64)];
    b2all[i] = v;
    return;
  }
  i -= B2ALL_ELEMS;
  if (i < W1M_ELEMS) {
    int jj = i & 7;
    int c  = (i >> 3) & 15;
    int kg = (i >> 7) & 7;
    int t  = i >> 10;         // mat*7 + cn
    int cn = t % 7;
    int mat = t / 7;
    int j = cn*16 + c;        // hidden unit
    int k = kg*8 + jj;        // cond dim
    const float* W1 = (mat == 0) ? wW1 : (mat == 1) ? hW1 : sW1;
    W1m[i] = f2bf((j < HID) ? W1[k*HID + j] : 0.f);
    return;
  }
  i -= W1M_ELEMS;
  if (i < B1_ELEMS) {
    int mat = i / 112, col = i % 112;
    const float* b1 = (mat == 0) ? wb1 : (mat == 1) ? hb1 : sb1;
    b1all[i] = (col < HID) ? b1[col] : 0.f;
  }
}

__global__ __launch_bounds__(256, 2)
void spline_main(
    const float* __restrict__ X, const float* __restrict__ C,
    const int* __restrict__ pmask,
    const uint16_t* __restrict__ W2m, const float* __restrict__ b2all,
    const uint16_t* __restrict__ W1m, const float* __restrict__ b1all,
    float* __restrict__ Y, float* __restrict__ LADJ)
{
  __shared__ union {
    float cond_s[ROWS*68];       // 8704 B (phase 0/1 only)
    float Ls[4][ROWS*100];       // 51200 B (main loop)
  } U;
  __shared__ uint16_t At[3*16*ROWS*8];  // 24576 B, persistent
  __shared__ float LjLds[4][ROWS];      // 512 B   (total ~76.3 KB)

  const int tid = threadIdx.x;
  const int r0 = blockIdx.x * ROWS;
  const int lane = tid & 63, wv = tid >> 6;
  const int l15 = lane & 15, lkg = lane >> 4;
  const int hb = lane >> 5;          // 0: widths pipe, 1: heights pipe
  const int srow = lane & 31;

  // ---- phase 0: stage cond tile ----
  for (int i = tid; i < ROWS*CDIM; i += 256) {
    int r = i >> 6, c = i & 63;
    U.cond_s[r*68 + c] = C[(size_t)(r0 + r)*CDIM + c];
  }
  __syncthreads();

  // ---- phase 1: hidden = silu(cond@W1+b1) via MFMA -> At (bf16 A-frag layout) ----
  {
    bf16x8 cf[2][2];
#pragma unroll
    for (int m = 0; m < 2; ++m)
#pragma unroll
      for (int ks = 0; ks < 2; ++ks) {
        const float* cp = &U.cond_s[(m*16 + l15)*68 + ks*32 + lkg*8];
        float4 c0 = *(const float4*)cp;
        float4 c1 = *(const float4*)(cp + 4);
        union { uint16_t u[8]; bf16x8 v; } tmp;
        tmp.u[0]=f2bf(c0.x); tmp.u[1]=f2bf(c0.y); tmp.u[2]=f2bf(c0.z); tmp.u[3]=f2bf(c0.w);
        tmp.u[4]=f2bf(c1.x); tmp.u[5]=f2bf(c1.y); tmp.u[6]=f2bf(c1.z); tmp.u[7]=f2bf(c1.w);
        cf[m][ks] = tmp.v;
      }
    for (int t = wv; t < 21; t += 4) {
      int mat = t / 7, cn = t % 7;
      const uint16_t* Wb = W1m + (size_t)(mat*7 + cn)*1024;
      bf16x8 wf[2];
#pragma unroll
      for (int ks = 0; ks < 2; ++ks)
        wf[ks] = *(const bf16x8*)&Wb[(ks*4 + lkg)*128 + l15*8];
      f32x4 h0 = {0.f,0.f,0.f,0.f}, h1 = {0.f,0.f,0.f,0.f};
#pragma unroll
      for (int ks = 0; ks < 2; ++ks) {
        h0 = __builtin_amdgcn_mfma_f32_16x16x32_bf16(cf[0][ks], wf[ks], h0, 0, 0, 0);
        h1 = __builtin_amdgcn_mfma_f32_16x16x32_bf16(cf[1][ks], wf[ks], h1, 0, 0, 0);
      }
      float bb = b1all[mat*112 + cn*16 + l15];
      int j = cn*16 + l15;
      int base = mat*4096 + (j >> 3)*256 + (j & 7);
#pragma unroll
      for (int r = 0; r < 4; ++r) {
        float a0 = h0[r] + bb;
        float v0 = a0 * __builtin_amdgcn_rcpf(1.f + __builtin_amdgcn_exp2f(-LOG2E*a0));
        At[base + (lkg*4 + r)*8] = f2bf(v0);
        float a1 = h1[r] + bb;
        float v1 = a1 * __builtin_amdgcn_rcpf(1.f + __builtin_amdgcn_exp2f(-LOG2E*a1));
        At[base + (16 + lkg*4 + r)*8] = f2bf(v1);
      }
    }
    // zero-fill At kg 14,15 (K-padding: A must be 0 there)
    for (int i2 = tid; i2 < 768; i2 += 256) {
      int mat = i2 >> 8, q = i2 & 255;
      *(uint32_t*)&At[mat*4096 + 14*256 + q*2] = 0u;
    }
  }
  __syncthreads();   // At complete; cond_s dead -> Ls region writable

  float* LsW = &U.Ls[wv][0];
  const int dbase = wv*16;
  float ladj2 = 0.f;
  float xq = 0.f; int pq = 0;

  // ---- spline for one dim, symmetric lanes (lo: widths+eval, hi: heights+slope2) ----
  auto SPLINE = [&](int d, float xv, int pm) {
    const float* Lr = LsW + srow*100 + hb*32;
    float e[32];
#pragma unroll
    for (int q = 0; q < 8; ++q) *(float4*)&e[4*q] = *(const float4*)(Lr + 4*q);
    // tree sum
    float s16[16];
#pragma unroll
    for (int k = 0; k < 16; ++k) s16[k] = e[2*k] + e[2*k+1];
#pragma unroll
    for (int k = 0; k < 8; ++k) s16[k] = s16[2*k] + s16[2*k+1];
#pragma unroll
    for (int k = 0; k < 4; ++k) s16[k] = s16[2*k] + s16[2*k+1];
    float S = (s16[0] + s16[1]) + (s16[2] + s16[3]);
    float rs = __builtin_amdgcn_rcpf(S);
    // binsearch (lo lanes meaningful; hi lanes harmless garbage)
    float Aa = (xv + 1.f) * 0.7352941176470588f * S;   // (x+1)/(2*0.68) * S
    float Uq = 0.014705882352941176f * S;              // 0.01/0.68 * S
    float T = Aa, Pc = 0.f, fidx = 0.f;
#pragma unroll
    for (int c = 1; c <= 31; ++c) {
      Pc += e[c-1]; T -= Uq;
      fidx = (Pc <= T) ? (float)c : fidx;
    }
    float foth = __shfl_xor(fidx, 32);
    float idxu = hb ? foth : fidx;       // broadcast lo's idx to hi
    // masked prefix (exact same fp-add order as cumsum) + e[idx] select
    float Psel = 0.f, esel = e[0];
#pragma unroll
    for (int c = 0; c < 32; ++c) {
      float cfv = (float)c;
      Psel += (cfv < idxu) ? e[c] : 0.f;
      esel  = (cfv == idxu) ? e[c] : esel;
    }
    float cK = fmaf(0.02f, idxu, -1.f) + 1.36f*rs*Psel;          // cwk / chk
    float wK = (idxu > 30.5f) ? (1.f - cK) : fmaf(1.36f*rs, esel, 0.02f);  // wk / hk
    // slope: lo takes d[idx], hi takes d[idx+1] (periodic tie at idx==31)
    int idxi = (int)idxu;
    int off = 64 + idxi + hb;
    if (hb && idxi == 31) off = pm ? 64 : 96;
    float sl = LsW[srow*100 + off];
    float dkv = fmaf(LN2, __builtin_amdgcn_logf(1.f + __builtin_amdgcn_exp2f(LOG2E*sl)), 0.01f);
    // exchange: lo receives hi's (chk, hk, dk1)
    float cO = __shfl_xor(cK, 32);
    float wO = __shfl_xor(wK, 32);
    float dO = __shfl_xor(dkv, 32);
    float cwk = cK, wk = wK, dk = dkv, chk = cO, hk = wO, dk1 = dO;
    float rw = __builtin_amdgcn_rcpf(wk);
    float th = (xv - cwk)*rw;
    float delta = hk*rw;
    float omt = 1.f - th, t1m = th*omt, th2 = th*th;
    float denom = fmaf(dk1 + dk - 2.f*delta, t1m, delta);
    float rden = __builtin_amdgcn_rcpf(denom);
    float yv = fmaf(hk*fmaf(delta, th2, dk*t1m), rden, chk);
    float dn2 = fmaf(dk1, th2, fmaf(2.f*delta, t1m, dk*omt*omt));
    ladj2 += 2.f*(__builtin_amdgcn_logf(delta) - __builtin_amdgcn_logf(denom))
           + __builtin_amdgcn_logf(dn2);
    if (!hb) Y[(size_t)(r0 + srow)*DIMS + d] = yv;
  };

  // ---- A-frag loader (one mat -> 8 regs) ----
  auto LOADA = [&](bf16x8 (&a2)[2][4], int mat) {
#pragma unroll
    for (int m = 0; m < 2; ++m)
#pragma unroll
      for (int ks = 0; ks < 4; ++ks)
        a2[m][ks] = *(const bf16x8*)&At[mat*4096 + (ks*4 + lkg)*256 + (m*16 + l15)*8];
  };

  // ---- per-cn GEMM tile: 8 MFMA + epilogue ----
  auto DO = [&](const bf16x8 (&afm)[2][4], const bf16x8 (&B)[4],
                float bb, int col, bool doexp) {
    f32x4 a0 = {bb,bb,bb,bb}, a1 = {bb,bb,bb,bb};
#pragma unroll
    for (int ks = 0; ks < 4; ++ks)
      a0 = __builtin_amdgcn_mfma_f32_16x16x32_bf16(afm[0][ks], B[ks], a0, 0, 0, 0);
#pragma unroll
    for (int ks = 0; ks < 4; ++ks)
      a1 = __builtin_amdgcn_mfma_f32_16x16x32_bf16(afm[1][ks], B[ks], a1, 0, 0, 0);
    if (doexp) {
#pragma unroll
      for (int r = 0; r < 4; ++r) {
        a0[r] = __builtin_amdgcn_exp2f(a0[r]);
        a1[r] = __builtin_amdgcn_exp2f(a1[r]);
      }
    }
    if (col < 97) {
#pragma unroll
      for (int r = 0; r < 4; ++r) {
        LsW[(lkg*4 + r)*100 + col]      = a0[r];
        LsW[(16 + lkg*4 + r)*100 + col] = a1[r];
      }
    }
  };

  // ---- main loop: 16 dims per wave, no barriers, 3-deep B pipeline ----
#pragma unroll 1
  for (int dd = 0; dd < 16; ++dd) {
    const int d = dbase + dd;
    const uint16_t* Bd = W2m + (size_t)d*DIM_STRIDE;
    auto LOADB = [&](bf16x8 (&dst)[4], int cn) {
#pragma unroll
      for (int ks = 0; ks < 4; ++ks) {
        int kgb = ks*4 + lkg; kgb = (kgb > 13) ? 13 : kgb;
        dst[ks] = *(const bf16x8*)&Bd[cn*CN_STRIDE + kgb*128 + l15*8];
      }
    };
    bf16x8 bA[4], bB[4], bC[4];
    LOADB(bA, 0); LOADB(bB, 1); LOADB(bC, 2);
    float bbv[7];
#pragma unroll
    for (int cn = 0; cn < 7; ++cn) bbv[cn] = b2all[d*128 + cn*16 + l15];
    float xn = X[(size_t)(r0 + srow)*DIMS + d];
    int pn = pmask[d];

    if (dd > 0) SPLINE(d - 1, xq, pq);   // ~600-cyc chain hides B-load latency
    xq = xn; pq = pn;

    bf16x8 afc[2][4];
    LOADA(afc, 0);
    DO(afc, bA, bbv[0], 0*16 + l15, true);  LOADB(bA, 3);
    DO(afc, bB, bbv[1], 1*16 + l15, true);  LOADB(bB, 4);
    LOADA(afc, 1);
    DO(afc, bC, bbv[2], 2*16 + l15, true);  LOADB(bC, 5);
    DO(afc, bA, bbv[3], 3*16 + l15, true);  LOADB(bA, 6);
    LOADA(afc, 2);
    DO(afc, bB, bbv[4], 4*16 + l15, false);
    DO(afc, bC, bbv[5], 5*16 + l15, false);
    DO(afc, bA, bbv[6], 6*16 + l15, false);
  }
  SPLINE(dbase + 15, xq, pq);

  if (!hb) LjLds[wv][srow] = ladj2;
  __syncthreads();
  if (tid < ROWS)
    LADJ[r0 + tid] = LN2 * ((LjLds[0][tid] + LjLds[1][tid]) + (LjLds[2][tid] + LjLds[3][tid]));
}

extern "C" void kernel_launch(void* const* d_in, const int* in_sizes, int n_in,
                              void* d_out, int out_size, void* d_ws, size_t ws_size,
                              hipStream_t stream) {
  const float* x     = (const float*)d_in[0];
  const float* cond  = (const float*)d_in[1];
  const int*   pmask = (const int*)d_in[2];
  const float* wW1 = (const float*)d_in[3];
  const float* wb1 = (const float*)d_in[4];
  const float* wW2 = (const float*)d_in[5];
  const float* wb2 = (const float*)d_in[6];
  const float* hW1 = (const float*)d_in[7];
  const float* hb1 = (const float*)d_in[8];
  const float* hW2 = (const float*)d_in[9];
  const float* hb2 = (const float*)d_in[10];
  const float* sW1 = (const float*)d_in[11];
  const float* sb1 = (const float*)d_in[12];
  const float* sW2 = (const float*)d_in[13];
  const float* sb2 = (const float*)d_in[14];

  uint16_t* W2m   = (uint16_t*)((char*)d_ws + W2M_OFF);
  float*    b2all = (float*)((char*)d_ws + B2ALL_OFF);
  uint16_t* W1m   = (uint16_t*)((char*)d_ws + W1M_OFF);
  float*    b1all = (float*)((char*)d_ws + B1_OFF);

  const int total = W2M_ELEMS + B2ALL_ELEMS + W1M_ELEMS + B1_ELEMS;
  repack_kernel<<<(total + 255)/256, 256, 0, stream>>>(
      wW2, wb2, hW2, hb2, sW2, sb2, wW1, hW1, sW1, wb1, hb1, sb1,
      W2m, b2all, W1m, b1all);

  float* Y = (float*)d_out;
  float* LADJ = Y + (size_t)M_TOTAL*DIMS;
  spline_main<<<M_TOTAL/ROWS, 256, 0, stream>>>(
      x, cond, pmask, W2m, b2all, W1m, b1all, Y, LADJ);
}